// Round 3
// baseline (639.749 us; speedup 1.0000x reference)
//
#include <hip/hip_runtime.h>
#include <math.h>

typedef unsigned short u16;
typedef short s8v __attribute__((ext_vector_type(8)));
typedef u16 u4v __attribute__((ext_vector_type(4)));
typedef float f4v __attribute__((ext_vector_type(4)));

#define MFMA16(a,b,c) __builtin_amdgcn_mfma_f32_16x16x32_bf16((a),(b),(c),0,0,0)
#define GLDS16(g, l) __builtin_amdgcn_global_load_lds( \
    (const __attribute__((address_space(1))) unsigned int*)(g), \
    (__attribute__((address_space(3))) unsigned int*)(l), 16, 0, 0)

#define N_TOK 2048
#define SEQ   1024

__device__ __forceinline__ u16 f2b(float f){
  union { float f; unsigned u; } v; v.f = f;
  return (u16)((v.u + 0x7FFFu + ((v.u >> 16) & 1u)) >> 16);
}
__device__ __forceinline__ float b2f(u16 b){
  union { unsigned u; float f; } v; v.u = ((unsigned)b) << 16; return v.f;
}
__device__ __forceinline__ float gelu_f(float x){
  return 0.5f*x*(1.0f + erff(x*0.70710678118654752f));
}

// ===================== RMSNorm (fp32 + bf16 out) =====================
__global__ __launch_bounds__(256) void rmsnorm_k(const float* __restrict__ x,
    const float* __restrict__ gamma, float* __restrict__ outf, u16* __restrict__ outb)
{
  const int t = blockIdx.x, tid = threadIdx.x;
  const float* xr = x + (size_t)t * 1024;
  float4 xv = *(const float4*)(xr + tid*4);
  float ss = xv.x*xv.x + xv.y*xv.y + xv.z*xv.z + xv.w*xv.w;
  #pragma unroll
  for (int off = 32; off; off >>= 1) ss += __shfl_down(ss, off);
  __shared__ float red[4];
  if ((tid & 63) == 0) red[tid >> 6] = ss;
  __syncthreads();
  float inv = rsqrtf((red[0]+red[1]+red[2]+red[3]) * (1.0f/1024.0f) + 1e-5f);
  float4 gv = *(const float4*)(gamma + tid*4);
  float4 o;
  o.x = xv.x*inv*gv.x; o.y = xv.y*inv*gv.y; o.z = xv.z*inv*gv.z; o.w = xv.w*inv*gv.w;
  *(float4*)(outf + (size_t)t*1024 + tid*4) = o;
  u4v ob = { f2b(o.x), f2b(o.y), f2b(o.z), f2b(o.w) };
  *(u4v*)(outb + (size_t)t*1024 + tid*4) = ob;
}

// ===================== RoPE cos/sin table: tab[s][2j]=cos, [2j+1]=sin =====================
__global__ __launch_bounds__(256) void ropetab_k(const float* __restrict__ theta, float* __restrict__ tab)
{
  int i = blockIdx.x*256 + threadIdx.x;   // i < SEQ*32
  int s = i >> 5, j = i & 31;
  float sn, cs;
  sincosf((float)s * theta[j], &sn, &cs);
  tab[(size_t)s*64 + 2*j]     = cs;
  tab[(size_t)s*64 + 2*j + 1] = sn;
}

// ===================== weight transpose+convert: W[K=1024][N=1024] f32 -> Wt[N][K] bf16 ==========
__device__ __forceinline__ void transT_body(const float* __restrict__ W, u16* __restrict__ Wt)
{
  __shared__ __align__(16) u16 T[64][68];
  const int tid = threadIdx.x;
  const int k0 = blockIdx.x*64, n0 = blockIdx.y*64;
  #pragma unroll
  for (int j = 0; j < 4; j++) {
    int q = j*256 + tid; int r = q >> 4, c4 = q & 15;
    float4 v = *(const float4*)(W + (size_t)(k0 + r)*1024 + n0 + c4*4);
    T[c4*4+0][r] = f2b(v.x); T[c4*4+1][r] = f2b(v.y);
    T[c4*4+2][r] = f2b(v.z); T[c4*4+3][r] = f2b(v.w);
  }
  __syncthreads();
  #pragma unroll
  for (int j = 0; j < 4; j++) {
    int q = j*256 + tid; int n = q >> 4, c4 = q & 15;
    u4v o = *(const u4v*)&T[n][c4*4];
    *(u4v*)(Wt + (size_t)(n0 + n)*1024 + k0 + c4*4) = o;
  }
}

__global__ __launch_bounds__(256) void transT6_k(
    const float* s0, const float* s1, const float* s2,
    const float* s3, const float* s4, const float* s5,
    u16* d0, u16* d1, u16* d2, u16* d3, u16* d4, u16* d5)
{
  const float* S; u16* D;
  switch (blockIdx.z) {
    case 0: S=s0; D=d0; break; case 1: S=s1; D=d1; break;
    case 2: S=s2; D=d2; break; case 3: S=s3; D=d3; break;
    case 4: S=s4; D=d4; break; default: S=s5; D=d5; break;
  }
  transT_body(S, D);
}

// ===================== V transpose: vb[token][h*64+hd] -> vt[(bh*64+hd)][s] ==========
__global__ __launch_bounds__(256) void transv_k(const u16* __restrict__ vb, u16* __restrict__ vt)
{
  __shared__ __align__(16) u16 T[64][72];
  const int tid = threadIdx.x;
  const int s0 = blockIdx.x*64, bh = blockIdx.y, b = bh>>4, h = bh&15;
  #pragma unroll
  for (int j = 0; j < 16; j++) {
    int q = j*256 + tid; int r = q >> 6, c = q & 63;
    T[c][r] = vb[(size_t)(b*SEQ + s0 + r)*1024 + h*64 + c];
  }
  __syncthreads();
  #pragma unroll
  for (int i = 0; i < 2; i++) {
    int q = tid*2 + i; int rr = q >> 3, c8 = q & 7;
    *(s8v*)(vt + (size_t)(bh*64 + rr)*1024 + s0 + c8*8) = *(const s8v*)&T[rr][c8*8];
  }
}

// ===================== MFMA GEMM (templated tile: BM x BN, BK=64, global_load_lds) ==========
// MODE 7: QKV fused (wsel = blockIdx.x>>3); q/k get RoPE applied in epilogue (theta = cos/sin table)
// MODE 3: outf = acc + bias + add1
// MODE 2: outb = bf16(gelu(acc+bias))
// MODE 4: outf = acc + bias + add1 + add2
// MODE 5: MoE up (worklist): gather rows via gidx, B from f32 expert W (pipelined), gelu -> outb
// MODE 6: MoE down (worklist): A at offs[e], B from f32 expert W (pipelined), gate*(acc+bias) -> outf
template<int MODE, int BM, int BN>
__global__ __launch_bounds__(256) void mmk(
    const u16* __restrict__ A,
    const u16* __restrict__ Wt0, const u16* __restrict__ Wt1, const u16* __restrict__ Wt2,
    const float* __restrict__ bias0, const float* __restrict__ bias1, const float* __restrict__ bias2,
    float* __restrict__ outf, u16* __restrict__ outb0, u16* __restrict__ outb1, u16* __restrict__ outb2,
    const float* __restrict__ add1, const float* __restrict__ add2,
    const int* __restrict__ gidx, const float* __restrict__ gatel,
    const int* __restrict__ counts, const int* __restrict__ offs,
    const int* __restrict__ wl, const int* __restrict__ ntl,
    const float* __restrict__ theta, const float* __restrict__ wf)
{
  constexpr bool EW = (MODE == 5 || MODE == 6);   // expert weights: f32 source, fused transpose
  constexpr int MF = BM/32, NF = BN/32;   // 16x16 frags per wave (wave tile = BM/2 x BN/2)
  constexpr int CA = BM/32, CB = BN/32;   // GLDS16 calls per wave for A / B
  constexpr int BST = EW ? 72 : 64;       // Bs row stride (elems)
  __shared__ __align__(16) u16 As[(EW ? 2 : 1)*BM*64];   // double-buffered for EW pipeline
  __shared__ __align__(16) u16 Bs[BN*BST];
  __shared__ int toks[(MODE==5) ? BM : 1];
  __shared__ float gts[(MODE==6) ? BM : 1];

  const int tid = threadIdx.x;
  const int wave = tid >> 6, lane = tid & 63, quad = lane >> 4, l15 = lane & 15;
  int row0 = blockIdx.y * BM;
  int col0 = blockIdx.x * BN;
  const u16* Wt = Wt0;
  const float* bias = bias0;
  const u16* Ab = A;
  const float* Wf = wf;
  int wsel = 0, e = 0, cnt = 0, off_e = 0;

  if (MODE == 7) {
    wsel = blockIdx.x >> 3;
    col0 = (blockIdx.x & 7) * BN;
    Wt   = (wsel == 0) ? Wt0 : ((wsel == 1) ? Wt1 : Wt2);
    bias = (wsel == 0) ? bias0 : ((wsel == 1) ? bias1 : bias2);
  }
  if (EW) {
    if ((int)blockIdx.y >= ntl[0]) return;
    const int w = wl[blockIdx.y];
    e = w >> 8;
    row0 = (w & 255) * BM;
    cnt = counts[e];
    Wf = wf + (size_t)e * 1024 * 1024;
    bias = bias0 + e * 1024;
    off_e = offs[e];
    if (MODE == 6) Ab = A + (size_t)off_e * 1024;
    if (tid < BM) {
      int ok = (row0 + tid) < cnt;
      if (MODE == 5) toks[tid] = ok ? gidx[e * N_TOK + row0 + tid] : 0;
      if (MODE == 6) gts[tid]  = ok ? gatel[e * N_TOK + row0 + tid] : 0.f;
    }
    __syncthreads();
  }

  // per-lane staging sources: each GLDS call covers 8 rows (8 lanes/row, 16B granules)
  const int lr8 = lane >> 3;          // 0..7 : row within 8-row group
  const int lk  = (lane & 7) * 8;     // k element offset (16B granule)
  const u16* aptr[CA];
  const u16* bptr[CB];
  #pragma unroll
  for (int c = 0; c < CA; c++) {
    const int ar = wave*(BM/4) + c*8 + lr8;   // local tile row 0..BM-1
    long garow;
    if (MODE == 5) {
      garow = toks[ar];
    } else if (MODE == 6) {
      int rr = row0 + ar; if (rr >= cnt) rr = cnt - 1; garow = rr;
    } else {
      garow = row0 + ar;
    }
    aptr[c] = Ab + (size_t)garow * 1024 + lk;
  }
  if (!EW) {
    #pragma unroll
    for (int c = 0; c < CB; c++) {
      const int br = wave*(BN/4) + c*8 + lr8;
      bptr[c] = Wt + (size_t)(col0 + br) * 1024 + lk;
    }
  }

  // EW B-staging geometry: thread owns n = tid&127, k-granules kg0..kg0+3
  const int ewn  = tid & 127;
  const int kg0  = (tid >> 7) * 4;
  const float* ewp = EW ? (Wf + (size_t)(kg0*8)*1024 + col0 + ewn) : nullptr;

  f4v acc[MF][NF];
  #pragma unroll
  for (int i = 0; i < MF; i++)
    #pragma unroll
    for (int j = 0; j < NF; j++)
      acc[i][j] = (f4v){0.f,0.f,0.f,0.f};

  const int wr = (wave >> 1) * (BM/2), wc = (wave & 1) * (BN/2);

  if (EW) {
    // ---- software-pipelined EW loop: loads for step k issued during step k-1's MFMA phase ----
    float fb[4][8];
    #pragma unroll
    for (int it = 0; it < 4; it++)
      #pragma unroll
      for (int i = 0; i < 8; i++)
        fb[it][i] = ewp[(size_t)(it*8 + i)*1024];
    #pragma unroll
    for (int c = 0; c < CA; c++) GLDS16(aptr[c], As + (wave*(BM/4) + c*8)*64);

    int buf = 0;
    for (int k0 = 0; k0 < 1024; k0 += 64) {
      __syncthreads();   // drains fb(k) + GLDS A(k); orders prev-step LDS reads
      #pragma unroll
      for (int it = 0; it < 4; it++) {
        s8v h;
        #pragma unroll
        for (int i = 0; i < 8; i++) h[i] = (short)f2b(fb[it][i]);
        *(s8v*)&Bs[ewn*BST + (kg0 + it)*8] = h;
      }
      __syncthreads();   // ds_writes visible (vmcnt already 0 here)
      if (k0 + 64 < 1024) {
        const float* wp = ewp + (size_t)(k0 + 64) * 1024;
        #pragma unroll
        for (int it = 0; it < 4; it++)
          #pragma unroll
          for (int i = 0; i < 8; i++)
            fb[it][i] = wp[(size_t)(it*8 + i)*1024];
        #pragma unroll
        for (int c = 0; c < CA; c++)
          GLDS16(aptr[c] + k0 + 64, As + ((buf^1)*BM + wave*(BM/4) + c*8)*64);
      }
      s8v af[2][MF], bfr[2][NF];
      #pragma unroll
      for (int ks = 0; ks < 2; ks++) {
        #pragma unroll
        for (int mt = 0; mt < MF; mt++) af[ks][mt]  = *(const s8v*)&As[(buf*BM + wr + mt*16 + l15)*64 + ks*32 + quad*8];
        #pragma unroll
        for (int nt = 0; nt < NF; nt++) bfr[ks][nt] = *(const s8v*)&Bs[(wc + nt*16 + l15)*BST + ks*32 + quad*8];
      }
      #pragma unroll
      for (int ks = 0; ks < 2; ks++)
        #pragma unroll
        for (int mt = 0; mt < MF; mt++)
          #pragma unroll
          for (int nt = 0; nt < NF; nt++)
            acc[mt][nt] = MFMA16(af[ks][mt], bfr[ks][nt], acc[mt][nt]);
      buf ^= 1;
    }
  } else {
    for (int k0 = 0; k0 < 1024; k0 += 64) {
      __syncthreads();
      #pragma unroll
      for (int c = 0; c < CA; c++) GLDS16(aptr[c] + k0, As + (wave*(BM/4) + c*8)*64);
      #pragma unroll
      for (int c = 0; c < CB; c++) GLDS16(bptr[c] + k0, Bs + (wave*(BN/4) + c*8)*64);
      __syncthreads();
      s8v af[2][MF], bfr[2][NF];
      #pragma unroll
      for (int ks = 0; ks < 2; ks++) {
        #pragma unroll
        for (int mt = 0; mt < MF; mt++) af[ks][mt]  = *(const s8v*)&As[(wr + mt*16 + l15)*64 + ks*32 + quad*8];
        #pragma unroll
        for (int nt = 0; nt < NF; nt++) bfr[ks][nt] = *(const s8v*)&Bs[(wc + nt*16 + l15)*BST + ks*32 + quad*8];
      }
      #pragma unroll
      for (int ks = 0; ks < 2; ks++)
        #pragma unroll
        for (int mt = 0; mt < MF; mt++)
          #pragma unroll
          for (int nt = 0; nt < NF; nt++)
            acc[mt][nt] = MFMA16(af[ks][mt], bfr[ks][nt], acc[mt][nt]);
    }
  }

  #pragma unroll
  for (int mt = 0; mt < MF; mt++) {
    #pragma unroll
    for (int reg = 0; reg < 4; reg++) {
      const int lr = wr + mt*16 + quad*4 + reg;
      const size_t gr = row0 + lr;
      #pragma unroll
      for (int nt = 0; nt < NF; nt++) {
        const int n = wc + nt*16 + l15 + col0;
        float v = acc[mt][nt][reg] + bias[n];
        if (MODE == 7) {
          if (wsel == 2) {
            outb2[gr*1024 + n] = f2b(v);
          } else {
            // fused RoPE: adjacent n live in adjacent lanes; theta = cos/sin table
            float pv = __shfl_xor(v, 1);
            const int hd = n & 63;
            const int j = hd >> 1;
            const int s = (int)(gr & (SEQ - 1));
            float2 t = *(const float2*)&theta[(size_t)s*64 + 2*j];
            float cs = t.x, sn = t.y;
            float res; int col;
            if (hd & 1) { res = pv*sn + v*cs; col = (n & ~63) | (32 + j); }
            else        { res = v*cs - pv*sn; col = (n & ~63) | j; }
            u16 bv = f2b(res);
            if (wsel == 0) outb0[gr*1024 + col] = bv;
            else           outb1[gr*1024 + col] = bv;
          }
        } else if (MODE == 3) {
          outf[gr*1024 + n] = v + add1[gr*1024 + n];
        } else if (MODE == 2) {
          outb0[gr*1024 + n] = f2b(gelu_f(v));
        } else if (MODE == 4) {
          outf[gr*1024 + n] = v + add1[gr*1024 + n] + add2[gr*1024 + n];
        } else if (MODE == 5) {
          if (row0 + lr < cnt)
            outb0[(size_t)(off_e + row0 + lr)*1024 + n] = f2b(gelu_f(v));
        } else if (MODE == 6) {
          if (row0 + lr < cnt)
            outf[(size_t)(off_e + row0 + lr)*1024 + n] = gts[lr] * v;
        }
      }
    }
  }
}

// ===================== MFMA flash attention (causal) =====================
__global__ __launch_bounds__(256) void attn_k(const u16* __restrict__ qg,
    const u16* __restrict__ kg, const u16* __restrict__ vtg, u16* __restrict__ ctx)
{
  // load-balance remap: CU gets blocks c and c+256 -> (qt, 15-qt) pairs (17 kt-tiles each)
  const int qt = (blockIdx.y < 16) ? blockIdx.x : (15 - blockIdx.x);
  const int bh = blockIdx.y, b = bh >> 4, h = bh & 15;
  const int tid = threadIdx.x, wave = tid >> 6, lane = tid & 63;
  const int quad = lane >> 4, l15 = lane & 15;
  __shared__ __align__(16) u16 Ks[64][72];
  __shared__ __align__(16) u16 Vt[64][72];
  __shared__ __align__(16) u16 Ps[4][16][72];

  s8v aq0, aq1;
  {
    const size_t qrow = (size_t)(b*SEQ + qt*64 + wave*16 + l15);
    aq0 = *(const s8v*)(qg + qrow*1024 + h*64 + quad*8);
    aq1 = *(const s8v*)(qg + qrow*1024 + h*64 + 32 + quad*8);
  }
  f4v oac[4];
  #pragma unroll
  for (int i = 0; i < 4; i++) oac[i] = (f4v){0.f,0.f,0.f,0.f};
  float mi[4] = {-INFINITY,-INFINITY,-INFINITY,-INFINITY};
  float li[4] = {0.f,0.f,0.f,0.f};

  for (int kt = 0; kt <= qt; kt++) {
    __syncthreads();
    #pragma unroll
    for (int ii = 0; ii < 2; ii++) {
      int c = tid*2 + ii, r = c >> 3, c8 = c & 7;
      *(s8v*)&Ks[r][c8*8] = *(const s8v*)(kg + (size_t)(b*SEQ + kt*64 + r)*1024 + h*64 + c8*8);
      *(s8v*)&Vt[r][c8*8] = *(const s8v*)(vtg + (size_t)(bh*64 + r)*1024 + kt*64 + c8*8);
    }
    __syncthreads();

    f4v s[4];
    #pragma unroll
    for (int nt = 0; nt < 4; nt++) {
      f4v z = (f4v){0.f,0.f,0.f,0.f};
      s8v bk0 = *(const s8v*)&Ks[nt*16 + l15][quad*8];
      s8v bk1 = *(const s8v*)&Ks[nt*16 + l15][32 + quad*8];
      z = MFMA16(aq0, bk0, z);
      z = MFMA16(aq1, bk1, z);
      s[nt] = z;
    }
    float sc[4][4];
    const int rowl = wave*16 + quad*4;
    #pragma unroll
    for (int nt = 0; nt < 4; nt++) {
      #pragma unroll
      for (int r = 0; r < 4; r++) {
        float v = s[nt][r] * 0.125f;
        if (kt == qt && (nt*16 + l15) > (rowl + r)) v = -INFINITY;
        sc[nt][r] = v;
      }
    }
    float alpha[4];
    #pragma unroll
    for (int r = 0; r < 4; r++) {
      float v0 = fmaxf(fmaxf(sc[0][r], sc[1][r]), fmaxf(sc[2][r], sc[3][r]));
      v0 = fmaxf(v0, __shfl_xor(v0, 1));
      v0 = fmaxf(v0, __shfl_xor(v0, 2));
      v0 = fmaxf(v0, __shfl_xor(v0, 4));
      v0 = fmaxf(v0, __shfl_xor(v0, 8));
      float mnew = fmaxf(mi[r], v0);
      alpha[r] = __expf(mi[r] - mnew);
      mi[r] = mnew;
    }
    float psum[4] = {0.f,0.f,0.f,0.f};
    #pragma unroll
    for (int nt = 0; nt < 4; nt++) {
      #pragma unroll
      for (int r = 0; r < 4; r++) {
        float p = __expf(sc[nt][r] - mi[r]);
        psum[r] += p;
        Ps[wave][quad*4 + r][nt*16 + l15] = f2b(p);
      }
    }
    #pragma unroll
    for (int r = 0; r < 4; r++) {
      float ps = psum[r];
      ps += __shfl_xor(ps, 1);
      ps += __shfl_xor(ps, 2);
      ps += __shfl_xor(ps, 4);
      ps += __shfl_xor(ps, 8);
      li[r] = li[r]*alpha[r] + ps;
    }
    #pragma unroll
    for (int ht = 0; ht < 4; ht++) {
      f4v o = oac[ht];
      o[0] *= alpha[0]; o[1] *= alpha[1]; o[2] *= alpha[2]; o[3] *= alpha[3];
      oac[ht] = o;
    }
    asm volatile("s_waitcnt lgkmcnt(0)" ::: "memory");
    s8v pf0 = *(const s8v*)&Ps[wave][l15][quad*8];
    s8v pf1 = *(const s8v*)&Ps[wave][l15][32 + quad*8];
    #pragma unroll
    for (int ht = 0; ht < 4; ht++) {
      s8v vf0 = *(const s8v*)&Vt[ht*16 + l15][quad*8];
      s8v vf1 = *(const s8v*)&Vt[ht*16 + l15][32 + quad*8];
      oac[ht] = MFMA16(pf0, vf0, oac[ht]);
      oac[ht] = MFMA16(pf1, vf1, oac[ht]);
    }
  }
  float inv[4];
  #pragma unroll
  for (int r = 0; r < 4; r++) inv[r] = 1.f / li[r];
  #pragma unroll
  for (int ht = 0; ht < 4; ht++) {
    #pragma unroll
    for (int r = 0; r < 4; r++) {
      size_t row = (size_t)(b*SEQ + qt*64 + wave*16 + quad*4 + r);
      ctx[row*1024 + h*64 + ht*16 + l15] = f2b(oac[ht][r] * inv[r]);
    }
  }
}

// ===================== Router + top-3 =====================
__global__ __launch_bounds__(256) void router_k(const float* __restrict__ an,
    const float* __restrict__ rw, const float* __restrict__ rb,
    int* __restrict__ counts, int* __restrict__ tok_list, float* __restrict__ gate_list,
    int* __restrict__ tok_e, int* __restrict__ tok_s)
{
  const int t = blockIdx.x, tid = threadIdx.x;
  const int e = tid & 31, ch = tid >> 5;
  float part = 0.f;
  if (e < 31) {
    const float* ar = an + (size_t)t*1024 + ch*128;
    const float* wp = rw + (size_t)(ch*128)*31 + e;
    #pragma unroll 8
    for (int d = 0; d < 128; d++) part += ar[d] * wp[d*31];
  }
  __shared__ float red[8][32];
  __shared__ float lgs[32];
  red[ch][e] = part;
  __syncthreads();
  if (tid < 31) {
    float s = 0.f;
    #pragma unroll
    for (int c = 0; c < 8; c++) s += red[c][tid];
    lgs[tid] = s + rb[tid];
  }
  __syncthreads();
  if (tid == 0) {
    float m = -1e30f;
    for (int i = 0; i < 31; i++) m = fmaxf(m, lgs[i]);
    float den = 0.f;
    for (int i = 0; i < 31; i++) den += __expf(lgs[i] - m);
    float invd = 1.f/den;
    unsigned used = 0;
    for (int kk = 0; kk < 3; kk++) {
      int best = 0; float bv = -3e30f;
      for (int i = 0; i < 31; i++) if (!((used>>i)&1u) && lgs[i] > bv) { bv = lgs[i]; best = i; }
      used |= (1u << best);
      float gate = __expf(lgs[best] - m) * invd;
      int slot = atomicAdd(&counts[best], 1);
      tok_list[best*N_TOK + slot] = t;
      gate_list[best*N_TOK + slot] = gate;
      tok_e[t*3 + kk] = best;
      tok_s[t*3 + kk] = slot;
    }
  }
}

// scan + build worklist of (expert, 64-row tile) pairs; sum ceil(cnt/64) <= 126
__global__ void scan_k(const int* __restrict__ counts, int* __restrict__ offs,
                       int* __restrict__ wl, int* __restrict__ ntl){
  if (threadIdx.x == 0) {
    int s = 0, nt = 0;
    for (int i = 0; i < 31; i++){
      offs[i] = s; s += counts[i];
      int t = (counts[i] + 63) >> 6;
      for (int r = 0; r < t; r++) wl[nt++] = (i << 8) | r;
    }
    ntl[0] = nt;
  }
}

// ===================== final gather-reduce: out[t] += sum_j mo[offs[e_j]+s_j] ==========
__global__ __launch_bounds__(256) void reduce_k(const float* __restrict__ mo,
    const int* __restrict__ tok_e, const int* __restrict__ tok_s,
    const int* __restrict__ offs, float* __restrict__ out)
{
  const int t = blockIdx.x, tid = threadIdx.x;
  float4 acc = *(const float4*)(out + (size_t)t*1024 + tid*4);
  #pragma unroll
  for (int j = 0; j < 3; j++) {
    int e = tok_e[t*3 + j], s = tok_s[t*3 + j];
    const float* row = mo + (size_t)(offs[e] + s) * 1024;
    float4 v = *(const float4*)(row + tid*4);
    acc.x += v.x; acc.y += v.y; acc.z += v.z; acc.w += v.w;
  }
  *(float4*)(out + (size_t)t*1024 + tid*4) = acc;
}

// ===================== launch =====================
extern "C" void kernel_launch(void* const* d_in, const int* in_sizes, int n_in,
                              void* d_out, int out_size, void* d_ws, size_t ws_size,
                              hipStream_t stream)
{
  const float* x      = (const float*)d_in[0];
  const float* theta  = (const float*)d_in[2];
  const float* gamma1 = (const float*)d_in[3];
  const float* gamma2 = (const float*)d_in[4];
  const float* q_w = (const float*)d_in[5];
  const float* q_b = (const float*)d_in[6];
  const float* k_w = (const float*)d_in[7];
  const float* k_b = (const float*)d_in[8];
  const float* v_w = (const float*)d_in[9];
  const float* v_b = (const float*)d_in[10];
  const float* o_w = (const float*)d_in[11];
  const float* o_b = (const float*)d_in[12];
  const float* router_w = (const float*)d_in[13];
  const float* router_b = (const float*)d_in[14];
  const float* sh_w1 = (const float*)d_in[15];
  const float* sh_b1 = (const float*)d_in[16];
  const float* sh_w2 = (const float*)d_in[17];
  const float* sh_b2 = (const float*)d_in[18];
  const float* re_w1 = (const float*)d_in[19];
  const float* re_b1 = (const float*)d_in[20];
  const float* re_w2 = (const float*)d_in[21];
  const float* re_b2 = (const float*)d_in[22];
  float* out = (float*)d_out;

  char* p = (char*)d_ws;
  auto alloc = [&](size_t bytes) -> void* {
    void* r = (void*)p; p += (bytes + 255) & ~(size_t)255; return r;
  };
  const size_t F32 = (size_t)N_TOK*1024*4;
  const size_t B16 = (size_t)N_TOK*1024*2;
  float* xn       = (float*)alloc(F32);
  float* attn_out = (float*)alloc(F32);
  float* an       = (float*)alloc(F32);
  float* mo       = (float*)alloc((size_t)3*N_TOK*1024*4);   // MoE gated partial rows
  u16* xnb  = (u16*)alloc(B16);
  u16* anb  = (u16*)alloc(B16);
  u16* vb   = (u16*)alloc(B16);
  u16* qb   = (u16*)alloc(B16);
  u16* kb   = (u16*)alloc(B16);
  u16* vt   = (u16*)alloc(B16);
  u16* ctxb = (u16*)alloc(B16);
  u16* shhb = (u16*)alloc(B16);
  u16* hmoe = (u16*)alloc((size_t)3*N_TOK*1024*2);
  u16* wtq  = (u16*)alloc((size_t)1024*1024*2);
  u16* wtk  = (u16*)alloc((size_t)1024*1024*2);
  u16* wtv  = (u16*)alloc((size_t)1024*1024*2);
  u16* wto  = (u16*)alloc((size_t)1024*1024*2);
  u16* wts1 = (u16*)alloc((size_t)1024*1024*2);
  u16* wts2 = (u16*)alloc((size_t)1024*1024*2);
  float* ropetab = (float*)alloc((size_t)SEQ*64*4);
  int* counts = (int*)alloc(128);
  int* offs   = (int*)alloc(128);
  int* tok_list  = (int*)alloc((size_t)31*N_TOK*4);
  float* gate_list = (float*)alloc((size_t)31*N_TOK*4);
  int* tok_e = (int*)alloc((size_t)N_TOK*3*4);
  int* tok_s = (int*)alloc((size_t)N_TOK*3*4);
  int* wl    = (int*)alloc(512);
  int* ntl   = (int*)alloc(64);

  hipMemsetAsync(counts, 0, 128, stream);

  transT6_k<<<dim3(16,16,6), 256, 0, stream>>>(q_w, k_w, v_w, o_w, sh_w1, sh_w2,
                                               wtq, wtk, wtv, wto, wts1, wts2);
  ropetab_k<<<(SEQ*32)/256, 256, 0, stream>>>(theta, ropetab);

  rmsnorm_k<<<N_TOK, 256, 0, stream>>>(x, gamma1, xn, xnb);

  // QKV fused (bf16 outputs, RoPE fused into q/k epilogue via table), 64x128 tiles
  mmk<7,64,128><<<dim3(24,32), 256, 0, stream>>>(xnb, wtq, wtk, wtv, q_b, k_b, v_b,
      nullptr, qb, kb, vb, nullptr, nullptr, nullptr, nullptr, nullptr, nullptr, nullptr, nullptr,
      ropetab, nullptr);

  transv_k<<<dim3(16,32), 256, 0, stream>>>(vb, vt);
  attn_k<<<dim3(16,32), 256, 0, stream>>>(qb, kb, vt, ctxb);

  // O-proj (+xn residual), 64x64 tiles
  mmk<3,64,64><<<dim3(16,32), 256, 0, stream>>>(ctxb, wto, nullptr, nullptr, o_b, nullptr, nullptr,
      attn_out, nullptr, nullptr, nullptr, xn, nullptr, nullptr, nullptr, nullptr, nullptr, nullptr, nullptr,
      nullptr, nullptr);

  rmsnorm_k<<<N_TOK, 256, 0, stream>>>(attn_out, gamma2, an, anb);

  // shared MLP up (gelu -> bf16), 64x64 tiles
  mmk<2,64,64><<<dim3(16,32), 256, 0, stream>>>(anb, wts1, nullptr, nullptr, sh_b1, nullptr, nullptr,
      nullptr, shhb, nullptr, nullptr, nullptr, nullptr, nullptr, nullptr, nullptr, nullptr, nullptr, nullptr,
      nullptr, nullptr);

  router_k<<<N_TOK, 256, 0, stream>>>(an, router_w, router_b, counts, tok_list, gate_list, tok_e, tok_s);
  scan_k<<<1, 32, 0, stream>>>(counts, offs, wl, ntl);

  // shared MLP down (+an +attn_out) -> d_out, 64x64 tiles
  mmk<4,64,64><<<dim3(16,32), 256, 0, stream>>>(shhb, wts2, nullptr, nullptr, sh_b2, nullptr, nullptr,
      out, nullptr, nullptr, nullptr, an, attn_out, nullptr, nullptr, nullptr, nullptr, nullptr, nullptr,
      nullptr, nullptr);

  // MoE up (worklist of 64-row tiles, gathered rows, f32 W fused-transpose pipelined, gelu -> hmoe)
  mmk<5,64,128><<<dim3(8,127), 256, 0, stream>>>(anb, nullptr, nullptr, nullptr, re_b1, nullptr, nullptr,
      nullptr, hmoe, nullptr, nullptr, nullptr, nullptr, tok_list, nullptr, counts, offs, wl, ntl,
      nullptr, re_w1);

  // MoE down: gated rows to scratch (no atomics), worklist tiles, f32 W fused-transpose pipelined
  mmk<6,64,128><<<dim3(8,127), 256, 0, stream>>>(hmoe, nullptr, nullptr, nullptr, re_b2, nullptr, nullptr,
      mo, nullptr, nullptr, nullptr, nullptr, nullptr, tok_list, gate_list, counts, offs, wl, ntl,
      nullptr, re_w2);

  // final per-token reduce of 3 expert rows into out
  reduce_k<<<N_TOK, 256, 0, stream>>>(mo, tok_e, tok_s, offs, out);
}

// Round 4
// 564.389 us; speedup vs baseline: 1.1335x; 1.1335x over previous
//
#include <hip/hip_runtime.h>
#include <math.h>

typedef unsigned short u16;
typedef short s8v __attribute__((ext_vector_type(8)));
typedef u16 u4v __attribute__((ext_vector_type(4)));
typedef float f4v __attribute__((ext_vector_type(4)));

#define MFMA16(a,b,c) __builtin_amdgcn_mfma_f32_16x16x32_bf16((a),(b),(c),0,0,0)
#define GLDS16(g, l) __builtin_amdgcn_global_load_lds( \
    (const __attribute__((address_space(1))) unsigned int*)(g), \
    (__attribute__((address_space(3))) unsigned int*)(l), 16, 0, 0)

#define N_TOK 2048
#define SEQ   1024

__device__ __forceinline__ u16 f2b(float f){
  union { float f; unsigned u; } v; v.f = f;
  return (u16)((v.u + 0x7FFFu + ((v.u >> 16) & 1u)) >> 16);
}
__device__ __forceinline__ float b2f(u16 b){
  union { unsigned u; float f; } v; v.u = ((unsigned)b) << 16; return v.f;
}
__device__ __forceinline__ float gelu_f(float x){
  return 0.5f*x*(1.0f + erff(x*0.70710678118654752f));
}

// ===================== RMSNorm (fp32 + bf16 out) =====================
__global__ __launch_bounds__(256) void rmsnorm_k(const float* __restrict__ x,
    const float* __restrict__ gamma, float* __restrict__ outf, u16* __restrict__ outb)
{
  const int t = blockIdx.x, tid = threadIdx.x;
  const float* xr = x + (size_t)t * 1024;
  float4 xv = *(const float4*)(xr + tid*4);
  float ss = xv.x*xv.x + xv.y*xv.y + xv.z*xv.z + xv.w*xv.w;
  #pragma unroll
  for (int off = 32; off; off >>= 1) ss += __shfl_down(ss, off);
  __shared__ float red[4];
  if ((tid & 63) == 0) red[tid >> 6] = ss;
  __syncthreads();
  float inv = rsqrtf((red[0]+red[1]+red[2]+red[3]) * (1.0f/1024.0f) + 1e-5f);
  float4 gv = *(const float4*)(gamma + tid*4);
  float4 o;
  o.x = xv.x*inv*gv.x; o.y = xv.y*inv*gv.y; o.z = xv.z*inv*gv.z; o.w = xv.w*inv*gv.w;
  *(float4*)(outf + (size_t)t*1024 + tid*4) = o;
  u4v ob = { f2b(o.x), f2b(o.y), f2b(o.z), f2b(o.w) };
  *(u4v*)(outb + (size_t)t*1024 + tid*4) = ob;
}

// ===================== RoPE cos/sin table: tab[s][2j]=cos, [2j+1]=sin =====================
__global__ __launch_bounds__(256) void ropetab_k(const float* __restrict__ theta, float* __restrict__ tab)
{
  int i = blockIdx.x*256 + threadIdx.x;   // i < SEQ*32
  int s = i >> 5, j = i & 31;
  float sn, cs;
  sincosf((float)s * theta[j], &sn, &cs);
  tab[(size_t)s*64 + 2*j]     = cs;
  tab[(size_t)s*64 + 2*j + 1] = sn;
}

// ===================== weight transpose+convert: W[K=1024][N=1024] f32 -> Wt[N][K] bf16 ==========
__device__ __forceinline__ void transT_body(const float* __restrict__ W, u16* __restrict__ Wt)
{
  __shared__ __align__(16) u16 T[64][68];
  const int tid = threadIdx.x;
  const int k0 = blockIdx.x*64, n0 = blockIdx.y*64;
  #pragma unroll
  for (int j = 0; j < 4; j++) {
    int q = j*256 + tid; int r = q >> 4, c4 = q & 15;
    float4 v = *(const float4*)(W + (size_t)(k0 + r)*1024 + n0 + c4*4);
    T[c4*4+0][r] = f2b(v.x); T[c4*4+1][r] = f2b(v.y);
    T[c4*4+2][r] = f2b(v.z); T[c4*4+3][r] = f2b(v.w);
  }
  __syncthreads();
  #pragma unroll
  for (int j = 0; j < 4; j++) {
    int q = j*256 + tid; int n = q >> 4, c4 = q & 15;
    u4v o = *(const u4v*)&T[n][c4*4];
    *(u4v*)(Wt + (size_t)(n0 + n)*1024 + k0 + c4*4) = o;
  }
}

__global__ __launch_bounds__(256) void transT6_k(
    const float* s0, const float* s1, const float* s2,
    const float* s3, const float* s4, const float* s5,
    u16* d0, u16* d1, u16* d2, u16* d3, u16* d4, u16* d5)
{
  const float* S; u16* D;
  switch (blockIdx.z) {
    case 0: S=s0; D=d0; break; case 1: S=s1; D=d1; break;
    case 2: S=s2; D=d2; break; case 3: S=s3; D=d3; break;
    case 4: S=s4; D=d4; break; default: S=s5; D=d5; break;
  }
  transT_body(S, D);
}

// ===================== V transpose: vb[token][h*64+hd] -> vt[(bh*64+hd)][s] ==========
__global__ __launch_bounds__(256) void transv_k(const u16* __restrict__ vb, u16* __restrict__ vt)
{
  __shared__ __align__(16) u16 T[64][72];
  const int tid = threadIdx.x;
  const int s0 = blockIdx.x*64, bh = blockIdx.y, b = bh>>4, h = bh&15;
  #pragma unroll
  for (int j = 0; j < 16; j++) {
    int q = j*256 + tid; int r = q >> 6, c = q & 63;
    T[c][r] = vb[(size_t)(b*SEQ + s0 + r)*1024 + h*64 + c];
  }
  __syncthreads();
  #pragma unroll
  for (int i = 0; i < 2; i++) {
    int q = tid*2 + i; int rr = q >> 3, c8 = q & 7;
    *(s8v*)(vt + (size_t)(bh*64 + rr)*1024 + s0 + c8*8) = *(const s8v*)&T[rr][c8*8];
  }
}

// ===================== MFMA GEMM (templated tile: BM x BN, BK=64, global_load_lds) ==========
// MODE 7: QKV fused (wsel = blockIdx.x>>3); q/k get RoPE applied in epilogue (theta = cos/sin table)
// MODE 3: outf = acc + bias + add1
// MODE 2: outb = bf16(gelu(acc+bias))
// MODE 4: outf = acc + bias + add1 + add2
// MODE 5: MoE up (worklist): gather rows via gidx, B from f32 expert W, gelu -> outb
// MODE 6: MoE down (worklist): A at offs[e], B from f32 expert W, gate*(acc+bias) -> outf
template<int MODE, int BM, int BN>
__global__ __launch_bounds__(256) void mmk(
    const u16* __restrict__ A,
    const u16* __restrict__ Wt0, const u16* __restrict__ Wt1, const u16* __restrict__ Wt2,
    const float* __restrict__ bias0, const float* __restrict__ bias1, const float* __restrict__ bias2,
    float* __restrict__ outf, u16* __restrict__ outb0, u16* __restrict__ outb1, u16* __restrict__ outb2,
    const float* __restrict__ add1, const float* __restrict__ add2,
    const int* __restrict__ gidx, const float* __restrict__ gatel,
    const int* __restrict__ counts, const int* __restrict__ offs,
    const int* __restrict__ wl, const int* __restrict__ ntl,
    const float* __restrict__ theta, const float* __restrict__ wf)
{
  constexpr bool EW = (MODE == 5 || MODE == 6);   // expert weights: f32 source, fused transpose
  constexpr int MF = BM/32, NF = BN/32;   // 16x16 frags per wave (wave tile = BM/2 x BN/2)
  constexpr int CA = BM/32, CB = BN/32;   // GLDS16 calls per wave for A / B
  constexpr int BST = EW ? 72 : 64;       // Bs row stride (elems); 72 keeps rows 16B-aligned
  __shared__ __align__(16) u16 As[BM*64];
  __shared__ __align__(16) u16 Bs[BN*BST];
  __shared__ int toks[(MODE==5) ? BM : 1];
  __shared__ float gts[(MODE==6) ? BM : 1];

  const int tid = threadIdx.x;
  const int wave = tid >> 6, lane = tid & 63, quad = lane >> 4, l15 = lane & 15;
  int row0 = blockIdx.y * BM;
  int col0 = blockIdx.x * BN;
  const u16* Wt = Wt0;
  const float* bias = bias0;
  const u16* Ab = A;
  const float* Wf = wf;
  int wsel = 0, e = 0, cnt = 0, off_e = 0;

  if (MODE == 7) {
    wsel = blockIdx.x >> 3;
    col0 = (blockIdx.x & 7) * BN;
    Wt   = (wsel == 0) ? Wt0 : ((wsel == 1) ? Wt1 : Wt2);
    bias = (wsel == 0) ? bias0 : ((wsel == 1) ? bias1 : bias2);
  }
  if (EW) {
    if ((int)blockIdx.y >= ntl[0]) return;
    const int w = wl[blockIdx.y];
    e = w >> 8;
    row0 = (w & 255) * BM;
    cnt = counts[e];
    Wf = wf + (size_t)e * 1024 * 1024;
    bias = bias0 + e * 1024;
    off_e = offs[e];
    if (MODE == 6) Ab = A + (size_t)off_e * 1024;
    if (tid < BM) {
      int ok = (row0 + tid) < cnt;
      if (MODE == 5) toks[tid] = ok ? gidx[e * N_TOK + row0 + tid] : 0;
      if (MODE == 6) gts[tid]  = ok ? gatel[e * N_TOK + row0 + tid] : 0.f;
    }
    __syncthreads();
  }

  // per-lane staging sources: each GLDS call covers 8 rows (8 lanes/row, 16B granules)
  const int lr8 = lane >> 3;          // 0..7 : row within 8-row group
  const int lk  = (lane & 7) * 8;     // k element offset (16B granule)
  const u16* aptr[CA];
  const u16* bptr[CB];
  #pragma unroll
  for (int c = 0; c < CA; c++) {
    const int ar = wave*(BM/4) + c*8 + lr8;   // local tile row 0..BM-1
    long garow;
    if (MODE == 5) {
      garow = toks[ar];
    } else if (MODE == 6) {
      int rr = row0 + ar; if (rr >= cnt) rr = cnt - 1; garow = rr;
    } else {
      garow = row0 + ar;
    }
    aptr[c] = Ab + (size_t)garow * 1024 + lk;
  }
  if (!EW) {
    #pragma unroll
    for (int c = 0; c < CB; c++) {
      const int br = wave*(BN/4) + c*8 + lr8;
      bptr[c] = Wt + (size_t)(col0 + br) * 1024 + lk;
    }
  }

  // EW B-staging geometry (BN==128): thread owns 4 consecutive n (n0 = (tid>>3)*4)
  // and 8 k-rows (kb*8 + kk, kb = tid&7). Loads are contiguous float4 along n.
  const int ewnb = tid >> 3;          // 0..31 -> n0 = ewnb*4
  const int ewkb = tid & 7;           // 0..7  -> k rows ewkb*8 .. ewkb*8+7
  const float* ewp = EW ? (Wf + (size_t)(ewkb*8)*1024 + col0 + ewnb*4) : nullptr;

  f4v acc[MF][NF];
  #pragma unroll
  for (int i = 0; i < MF; i++)
    #pragma unroll
    for (int j = 0; j < NF; j++)
      acc[i][j] = (f4v){0.f,0.f,0.f,0.f};

  const int wr = (wave >> 1) * (BM/2), wc = (wave & 1) * (BN/2);

  for (int k0 = 0; k0 < 1024; k0 += 64) {
    float4 f[EW ? 8 : 1];
    if (EW) {
      const float* wp = ewp + (size_t)k0 * 1024;
      #pragma unroll
      for (int kk = 0; kk < 8; kk++)
        f[kk] = *(const float4*)(wp + (size_t)kk * 1024);
    }
    __syncthreads();
    #pragma unroll
    for (int c = 0; c < CA; c++) GLDS16(aptr[c] + k0, As + (wave*(BM/4) + c*8)*64);
    if (EW) {
      #pragma unroll
      for (int j = 0; j < 4; j++) {
        s8v h;
        #pragma unroll
        for (int kk = 0; kk < 8; kk++) {
          float fv = (j == 0) ? f[kk].x : (j == 1) ? f[kk].y : (j == 2) ? f[kk].z : f[kk].w;
          h[kk] = (short)f2b(fv);
        }
        *(s8v*)&Bs[(ewnb*4 + j)*BST + ewkb*8] = h;
      }
    } else {
      #pragma unroll
      for (int c = 0; c < CB; c++) GLDS16(bptr[c] + k0, Bs + (wave*(BN/4) + c*8)*64);
    }
    __syncthreads();
    s8v af[2][MF], bfr[2][NF];
    #pragma unroll
    for (int ks = 0; ks < 2; ks++) {
      #pragma unroll
      for (int mt = 0; mt < MF; mt++) af[ks][mt]  = *(const s8v*)&As[(wr + mt*16 + l15)*64 + ks*32 + quad*8];
      #pragma unroll
      for (int nt = 0; nt < NF; nt++) bfr[ks][nt] = *(const s8v*)&Bs[(wc + nt*16 + l15)*BST + ks*32 + quad*8];
    }
    #pragma unroll
    for (int ks = 0; ks < 2; ks++)
      #pragma unroll
      for (int mt = 0; mt < MF; mt++)
        #pragma unroll
        for (int nt = 0; nt < NF; nt++)
          acc[mt][nt] = MFMA16(af[ks][mt], bfr[ks][nt], acc[mt][nt]);
  }

  #pragma unroll
  for (int mt = 0; mt < MF; mt++) {
    #pragma unroll
    for (int reg = 0; reg < 4; reg++) {
      const int lr = wr + mt*16 + quad*4 + reg;
      const size_t gr = row0 + lr;
      #pragma unroll
      for (int nt = 0; nt < NF; nt++) {
        const int n = wc + nt*16 + l15 + col0;
        float v = acc[mt][nt][reg] + bias[n];
        if (MODE == 7) {
          if (wsel == 2) {
            outb2[gr*1024 + n] = f2b(v);
          } else {
            // fused RoPE: adjacent n live in adjacent lanes; theta = cos/sin table
            float pv = __shfl_xor(v, 1);
            const int hd = n & 63;
            const int j = hd >> 1;
            const int s = (int)(gr & (SEQ - 1));
            float2 t = *(const float2*)&theta[(size_t)s*64 + 2*j];
            float cs = t.x, sn = t.y;
            float res; int col;
            if (hd & 1) { res = pv*sn + v*cs; col = (n & ~63) | (32 + j); }
            else        { res = v*cs - pv*sn; col = (n & ~63) | j; }
            u16 bv = f2b(res);
            if (wsel == 0) outb0[gr*1024 + col] = bv;
            else           outb1[gr*1024 + col] = bv;
          }
        } else if (MODE == 3) {
          outf[gr*1024 + n] = v + add1[gr*1024 + n];
        } else if (MODE == 2) {
          outb0[gr*1024 + n] = f2b(gelu_f(v));
        } else if (MODE == 4) {
          outf[gr*1024 + n] = v + add1[gr*1024 + n] + add2[gr*1024 + n];
        } else if (MODE == 5) {
          if (row0 + lr < cnt)
            outb0[(size_t)(off_e + row0 + lr)*1024 + n] = f2b(gelu_f(v));
        } else if (MODE == 6) {
          if (row0 + lr < cnt)
            outf[(size_t)(off_e + row0 + lr)*1024 + n] = gts[lr] * v;
        }
      }
    }
  }
}

// ===================== MFMA flash attention (causal) =====================
__global__ __launch_bounds__(256) void attn_k(const u16* __restrict__ qg,
    const u16* __restrict__ kg, const u16* __restrict__ vtg, u16* __restrict__ ctx)
{
  // load-balance remap: CU gets blocks c and c+256 -> (qt, 15-qt) pairs (17 kt-tiles each)
  const int qt = (blockIdx.y < 16) ? blockIdx.x : (15 - blockIdx.x);
  const int bh = blockIdx.y, b = bh >> 4, h = bh & 15;
  const int tid = threadIdx.x, wave = tid >> 6, lane = tid & 63;
  const int quad = lane >> 4, l15 = lane & 15;
  __shared__ __align__(16) u16 Ks[64][72];
  __shared__ __align__(16) u16 Vt[64][72];
  __shared__ __align__(16) u16 Ps[4][16][72];

  s8v aq0, aq1;
  {
    const size_t qrow = (size_t)(b*SEQ + qt*64 + wave*16 + l15);
    aq0 = *(const s8v*)(qg + qrow*1024 + h*64 + quad*8);
    aq1 = *(const s8v*)(qg + qrow*1024 + h*64 + 32 + quad*8);
  }
  f4v oac[4];
  #pragma unroll
  for (int i = 0; i < 4; i++) oac[i] = (f4v){0.f,0.f,0.f,0.f};
  float mi[4] = {-INFINITY,-INFINITY,-INFINITY,-INFINITY};
  float li[4] = {0.f,0.f,0.f,0.f};

  for (int kt = 0; kt <= qt; kt++) {
    __syncthreads();
    #pragma unroll
    for (int ii = 0; ii < 2; ii++) {
      int c = tid*2 + ii, r = c >> 3, c8 = c & 7;
      *(s8v*)&Ks[r][c8*8] = *(const s8v*)(kg + (size_t)(b*SEQ + kt*64 + r)*1024 + h*64 + c8*8);
      *(s8v*)&Vt[r][c8*8] = *(const s8v*)(vtg + (size_t)(bh*64 + r)*1024 + kt*64 + c8*8);
    }
    __syncthreads();

    f4v s[4];
    #pragma unroll
    for (int nt = 0; nt < 4; nt++) {
      f4v z = (f4v){0.f,0.f,0.f,0.f};
      s8v bk0 = *(const s8v*)&Ks[nt*16 + l15][quad*8];
      s8v bk1 = *(const s8v*)&Ks[nt*16 + l15][32 + quad*8];
      z = MFMA16(aq0, bk0, z);
      z = MFMA16(aq1, bk1, z);
      s[nt] = z;
    }
    float sc[4][4];
    const int rowl = wave*16 + quad*4;
    #pragma unroll
    for (int nt = 0; nt < 4; nt++) {
      #pragma unroll
      for (int r = 0; r < 4; r++) {
        float v = s[nt][r] * 0.125f;
        if (kt == qt && (nt*16 + l15) > (rowl + r)) v = -INFINITY;
        sc[nt][r] = v;
      }
    }
    float alpha[4];
    #pragma unroll
    for (int r = 0; r < 4; r++) {
      float v0 = fmaxf(fmaxf(sc[0][r], sc[1][r]), fmaxf(sc[2][r], sc[3][r]));
      v0 = fmaxf(v0, __shfl_xor(v0, 1));
      v0 = fmaxf(v0, __shfl_xor(v0, 2));
      v0 = fmaxf(v0, __shfl_xor(v0, 4));
      v0 = fmaxf(v0, __shfl_xor(v0, 8));
      float mnew = fmaxf(mi[r], v0);
      alpha[r] = __expf(mi[r] - mnew);
      mi[r] = mnew;
    }
    float psum[4] = {0.f,0.f,0.f,0.f};
    #pragma unroll
    for (int nt = 0; nt < 4; nt++) {
      #pragma unroll
      for (int r = 0; r < 4; r++) {
        float p = __expf(sc[nt][r] - mi[r]);
        psum[r] += p;
        Ps[wave][quad*4 + r][nt*16 + l15] = f2b(p);
      }
    }
    #pragma unroll
    for (int r = 0; r < 4; r++) {
      float ps = psum[r];
      ps += __shfl_xor(ps, 1);
      ps += __shfl_xor(ps, 2);
      ps += __shfl_xor(ps, 4);
      ps += __shfl_xor(ps, 8);
      li[r] = li[r]*alpha[r] + ps;
    }
    #pragma unroll
    for (int ht = 0; ht < 4; ht++) {
      f4v o = oac[ht];
      o[0] *= alpha[0]; o[1] *= alpha[1]; o[2] *= alpha[2]; o[3] *= alpha[3];
      oac[ht] = o;
    }
    asm volatile("s_waitcnt lgkmcnt(0)" ::: "memory");
    s8v pf0 = *(const s8v*)&Ps[wave][l15][quad*8];
    s8v pf1 = *(const s8v*)&Ps[wave][l15][32 + quad*8];
    #pragma unroll
    for (int ht = 0; ht < 4; ht++) {
      s8v vf0 = *(const s8v*)&Vt[ht*16 + l15][quad*8];
      s8v vf1 = *(const s8v*)&Vt[ht*16 + l15][32 + quad*8];
      oac[ht] = MFMA16(pf0, vf0, oac[ht]);
      oac[ht] = MFMA16(pf1, vf1, oac[ht]);
    }
  }
  float inv[4];
  #pragma unroll
  for (int r = 0; r < 4; r++) inv[r] = 1.f / li[r];
  #pragma unroll
  for (int ht = 0; ht < 4; ht++) {
    #pragma unroll
    for (int r = 0; r < 4; r++) {
      size_t row = (size_t)(b*SEQ + qt*64 + wave*16 + quad*4 + r);
      ctx[row*1024 + h*64 + ht*16 + l15] = f2b(oac[ht][r] * inv[r]);
    }
  }
}

// ===================== Router + top-3 =====================
__global__ __launch_bounds__(256) void router_k(const float* __restrict__ an,
    const float* __restrict__ rw, const float* __restrict__ rb,
    int* __restrict__ counts, int* __restrict__ tok_list, float* __restrict__ gate_list,
    int* __restrict__ tok_e, int* __restrict__ tok_s)
{
  const int t = blockIdx.x, tid = threadIdx.x;
  const int e = tid & 31, ch = tid >> 5;
  float part = 0.f;
  if (e < 31) {
    const float* ar = an + (size_t)t*1024 + ch*128;
    const float* wp = rw + (size_t)(ch*128)*31 + e;
    #pragma unroll 8
    for (int d = 0; d < 128; d++) part += ar[d] * wp[d*31];
  }
  __shared__ float red[8][32];
  __shared__ float lgs[32];
  red[ch][e] = part;
  __syncthreads();
  if (tid < 31) {
    float s = 0.f;
    #pragma unroll
    for (int c = 0; c < 8; c++) s += red[c][tid];
    lgs[tid] = s + rb[tid];
  }
  __syncthreads();
  if (tid == 0) {
    float m = -1e30f;
    for (int i = 0; i < 31; i++) m = fmaxf(m, lgs[i]);
    float den = 0.f;
    for (int i = 0; i < 31; i++) den += __expf(lgs[i] - m);
    float invd = 1.f/den;
    unsigned used = 0;
    for (int kk = 0; kk < 3; kk++) {
      int best = 0; float bv = -3e30f;
      for (int i = 0; i < 31; i++) if (!((used>>i)&1u) && lgs[i] > bv) { bv = lgs[i]; best = i; }
      used |= (1u << best);
      float gate = __expf(lgs[best] - m) * invd;
      int slot = atomicAdd(&counts[best], 1);
      tok_list[best*N_TOK + slot] = t;
      gate_list[best*N_TOK + slot] = gate;
      tok_e[t*3 + kk] = best;
      tok_s[t*3 + kk] = slot;
    }
  }
}

// scan + build worklist of (expert, 128-row tile) pairs; sum ceil(cnt/128) <= 79
__global__ void scan_k(const int* __restrict__ counts, int* __restrict__ offs,
                       int* __restrict__ wl, int* __restrict__ ntl){
  if (threadIdx.x == 0) {
    int s = 0, nt = 0;
    for (int i = 0; i < 31; i++){
      offs[i] = s; s += counts[i];
      int t = (counts[i] + 127) >> 7;
      for (int r = 0; r < t; r++) wl[nt++] = (i << 8) | r;
    }
    ntl[0] = nt;
  }
}

// ===================== final gather-reduce: out[t] += sum_j mo[offs[e_j]+s_j] ==========
__global__ __launch_bounds__(256) void reduce_k(const float* __restrict__ mo,
    const int* __restrict__ tok_e, const int* __restrict__ tok_s,
    const int* __restrict__ offs, float* __restrict__ out)
{
  const int t = blockIdx.x, tid = threadIdx.x;
  float4 acc = *(const float4*)(out + (size_t)t*1024 + tid*4);
  #pragma unroll
  for (int j = 0; j < 3; j++) {
    int e = tok_e[t*3 + j], s = tok_s[t*3 + j];
    const float* row = mo + (size_t)(offs[e] + s) * 1024;
    float4 v = *(const float4*)(row + tid*4);
    acc.x += v.x; acc.y += v.y; acc.z += v.z; acc.w += v.w;
  }
  *(float4*)(out + (size_t)t*1024 + tid*4) = acc;
}

// ===================== launch =====================
extern "C" void kernel_launch(void* const* d_in, const int* in_sizes, int n_in,
                              void* d_out, int out_size, void* d_ws, size_t ws_size,
                              hipStream_t stream)
{
  const float* x      = (const float*)d_in[0];
  const float* theta  = (const float*)d_in[2];
  const float* gamma1 = (const float*)d_in[3];
  const float* gamma2 = (const float*)d_in[4];
  const float* q_w = (const float*)d_in[5];
  const float* q_b = (const float*)d_in[6];
  const float* k_w = (const float*)d_in[7];
  const float* k_b = (const float*)d_in[8];
  const float* v_w = (const float*)d_in[9];
  const float* v_b = (const float*)d_in[10];
  const float* o_w = (const float*)d_in[11];
  const float* o_b = (const float*)d_in[12];
  const float* router_w = (const float*)d_in[13];
  const float* router_b = (const float*)d_in[14];
  const float* sh_w1 = (const float*)d_in[15];
  const float* sh_b1 = (const float*)d_in[16];
  const float* sh_w2 = (const float*)d_in[17];
  const float* sh_b2 = (const float*)d_in[18];
  const float* re_w1 = (const float*)d_in[19];
  const float* re_b1 = (const float*)d_in[20];
  const float* re_w2 = (const float*)d_in[21];
  const float* re_b2 = (const float*)d_in[22];
  float* out = (float*)d_out;

  char* p = (char*)d_ws;
  auto alloc = [&](size_t bytes) -> void* {
    void* r = (void*)p; p += (bytes + 255) & ~(size_t)255; return r;
  };
  const size_t F32 = (size_t)N_TOK*1024*4;
  const size_t B16 = (size_t)N_TOK*1024*2;
  float* xn       = (float*)alloc(F32);
  float* attn_out = (float*)alloc(F32);
  float* an       = (float*)alloc(F32);
  float* mo       = (float*)alloc((size_t)3*N_TOK*1024*4);   // MoE gated partial rows
  u16* xnb  = (u16*)alloc(B16);
  u16* anb  = (u16*)alloc(B16);
  u16* vb   = (u16*)alloc(B16);
  u16* qb   = (u16*)alloc(B16);
  u16* kb   = (u16*)alloc(B16);
  u16* vt   = (u16*)alloc(B16);
  u16* ctxb = (u16*)alloc(B16);
  u16* shhb = (u16*)alloc(B16);
  u16* hmoe = (u16*)alloc((size_t)3*N_TOK*1024*2);
  u16* wtq  = (u16*)alloc((size_t)1024*1024*2);
  u16* wtk  = (u16*)alloc((size_t)1024*1024*2);
  u16* wtv  = (u16*)alloc((size_t)1024*1024*2);
  u16* wto  = (u16*)alloc((size_t)1024*1024*2);
  u16* wts1 = (u16*)alloc((size_t)1024*1024*2);
  u16* wts2 = (u16*)alloc((size_t)1024*1024*2);
  float* ropetab = (float*)alloc((size_t)SEQ*64*4);
  int* counts = (int*)alloc(128);
  int* offs   = (int*)alloc(128);
  int* tok_list  = (int*)alloc((size_t)31*N_TOK*4);
  float* gate_list = (float*)alloc((size_t)31*N_TOK*4);
  int* tok_e = (int*)alloc((size_t)N_TOK*3*4);
  int* tok_s = (int*)alloc((size_t)N_TOK*3*4);
  int* wl    = (int*)alloc(512);
  int* ntl   = (int*)alloc(64);

  hipMemsetAsync(counts, 0, 128, stream);

  transT6_k<<<dim3(16,16,6), 256, 0, stream>>>(q_w, k_w, v_w, o_w, sh_w1, sh_w2,
                                               wtq, wtk, wtv, wto, wts1, wts2);
  ropetab_k<<<(SEQ*32)/256, 256, 0, stream>>>(theta, ropetab);

  rmsnorm_k<<<N_TOK, 256, 0, stream>>>(x, gamma1, xn, xnb);

  // QKV fused (bf16 outputs, RoPE fused into q/k epilogue via table), 64x128 tiles
  mmk<7,64,128><<<dim3(24,32), 256, 0, stream>>>(xnb, wtq, wtk, wtv, q_b, k_b, v_b,
      nullptr, qb, kb, vb, nullptr, nullptr, nullptr, nullptr, nullptr, nullptr, nullptr, nullptr,
      ropetab, nullptr);

  transv_k<<<dim3(16,32), 256, 0, stream>>>(vb, vt);
  attn_k<<<dim3(16,32), 256, 0, stream>>>(qb, kb, vt, ctxb);

  // O-proj (+xn residual), 64x64 tiles
  mmk<3,64,64><<<dim3(16,32), 256, 0, stream>>>(ctxb, wto, nullptr, nullptr, o_b, nullptr, nullptr,
      attn_out, nullptr, nullptr, nullptr, xn, nullptr, nullptr, nullptr, nullptr, nullptr, nullptr, nullptr,
      nullptr, nullptr);

  rmsnorm_k<<<N_TOK, 256, 0, stream>>>(attn_out, gamma2, an, anb);

  // shared MLP up (gelu -> bf16), 64x64 tiles
  mmk<2,64,64><<<dim3(16,32), 256, 0, stream>>>(anb, wts1, nullptr, nullptr, sh_b1, nullptr, nullptr,
      nullptr, shhb, nullptr, nullptr, nullptr, nullptr, nullptr, nullptr, nullptr, nullptr, nullptr, nullptr,
      nullptr, nullptr);

  router_k<<<N_TOK, 256, 0, stream>>>(an, router_w, router_b, counts, tok_list, gate_list, tok_e, tok_s);
  scan_k<<<1, 32, 0, stream>>>(counts, offs, wl, ntl);

  // shared MLP down (+an +attn_out) -> d_out, 64x64 tiles
  mmk<4,64,64><<<dim3(16,32), 256, 0, stream>>>(shhb, wts2, nullptr, nullptr, sh_b2, nullptr, nullptr,
      out, nullptr, nullptr, nullptr, an, attn_out, nullptr, nullptr, nullptr, nullptr, nullptr, nullptr,
      nullptr, nullptr);

  // MoE up (worklist of 128-row tiles, gathered rows, f32 W fused-transpose, gelu -> hmoe)
  mmk<5,128,128><<<dim3(8,79), 256, 0, stream>>>(anb, nullptr, nullptr, nullptr, re_b1, nullptr, nullptr,
      nullptr, hmoe, nullptr, nullptr, nullptr, nullptr, tok_list, nullptr, counts, offs, wl, ntl,
      nullptr, re_w1);

  // MoE down: gated rows to scratch (no atomics), worklist 128-row tiles, f32 W fused-transpose
  mmk<6,128,128><<<dim3(8,79), 256, 0, stream>>>(hmoe, nullptr, nullptr, nullptr, re_b2, nullptr, nullptr,
      mo, nullptr, nullptr, nullptr, nullptr, nullptr, tok_list, gate_list, counts, offs, wl, ntl,
      nullptr, re_w2);

  // final per-token reduce of 3 expert rows into out
  reduce_k<<<N_TOK, 256, 0, stream>>>(mo, tok_e, tok_s, offs, out);
}